// Round 1
// baseline (106.860 us; speedup 1.0000x reference)
//
#include <hip/hip_runtime.h>
#include <math.h>

#define SPLIT 8
static constexpr int HH = 200, WW = 200, NPL = 256; // planes k = 0..256

__device__ __forceinline__ float alpha_of(float k, float sp, float src, float sdd) {
    return (k * sp - src) / sdd;   // same expression as reference: (k*spacing - src)/sdd
}

__global__ __launch_bounds__(256)
void drr_kernel(const float* __restrict__ vol,
                const float* __restrict__ spacing,
                const float* __restrict__ sdrP,
                const float* __restrict__ thetaP,
                const float* __restrict__ phiP,
                const float* __restrict__ gammaP,
                const float* __restrict__ bxP,
                const float* __restrict__ byP,
                const float* __restrict__ bzP,
                float* __restrict__ out)
{
    const int tid = blockIdx.x * blockDim.x + threadIdx.x;
    const int ray = tid / SPLIT;
    const int seg = tid % SPLIT;
    if (ray >= HH * WW) return;
    const int it = ray / WW, is = ray % WW;

    const float sdr = sdrP[0];
    const float th = thetaP[0], ph = phiP[0], ga = gammaP[0];
    const float ct = cosf(th), st = sinf(th);
    const float cp = cosf(ph), sp = sinf(ph);
    const float cg = cosf(ga), sg = sinf(ga);

    // rotation = Rz @ Ry @ Rx
    const float rot[3][3] = {
        { ct*cp, ct*sp*sg - st*cg, ct*sp*cg + st*sg },
        { st*cp, st*sp*sg + ct*cg, st*sp*cg - ct*sg },
        { -sp,   cp*sg,            cp*cg            }
    };

    float source[3], u[3], v[3], trans[3];
    trans[0] = bxP[0]; trans[1] = byP[0]; trans[2] = bzP[0];
    for (int a = 0; a < 3; ++a) {
        // R = sdr * rot; source = R[:,0]; u = R[:,1]/sdr; v = R[:,2]/sdr (match f32 roundtrip)
        source[a] = sdr * rot[a][0];
        u[a] = (sdr * rot[a][1]) / sdr;
        v[a] = (sdr * rot[a][2]) / sdr;
    }

    const float tc = (float)(it - HH/2 + 1) * 2.0f;   // DELX
    const float sc = (float)(is - WW/2 + 1) * 2.0f;   // DELY

    float src[3], sdd[3], spn[3];
    float nrm2 = 0.0f;
    for (int a = 0; a < 3; ++a) {
        spn[a] = spacing[a];
        src[a] = source[a] + trans[a];
        float tg = tc * u[a] + sc * v[a];
        tg = tg - source[a];     // + center
        tg = tg + trans[a];
        float d = (tg - src[a]) + 1e-8f;   // sdd = tgt - src + EPS
        sdd[a] = d;
        nrm2 += d * d;
    }

    float amin = -INFINITY, amax = INFINITY;
    for (int a = 0; a < 3; ++a) {
        float a0 = (0.0f - src[a]) / sdd[a];
        float a1 = (256.0f * spn[a] - src[a]) / sdd[a];
        amin = fmaxf(amin, fminf(a0, a1));
        amax = fminf(amax, fmaxf(a0, a1));
    }

    float acc = 0.0f;
    if (amax > amin) {
        // Segment window (blo, bhi]; identical boundary arithmetic in all lanes of a ray.
        const float blo = (seg == 0) ? amin
                        : amin + (amax - amin) * ((float)seg / (float)SPLIT);
        const float bhi = (seg == SPLIT - 1) ? amax
                        : amin + (amax - amin) * ((float)(seg + 1) / (float)SPLIT);

        int   kcur[3], kstp[3];
        float nexta[3];
        float prev = -INFINITY;   // largest in-range alpha <= blo (the "previous" sorted element)

        for (int a = 0; a < 3; ++a) {
            const float sd = sdd[a], sr = src[a], spv = spn[a];
            const bool pos = sd > 0.0f;
            kstp[a] = pos ? 1 : -1;
            const float kf = (blo * sd + sr) / spv;   // analytic seed
            int kk;
            if (pos) {   // alpha increases with k; pointer = smallest k with alpha(k) > blo
                kk = (int)floorf(kf) + 1;
                kk = kk < 0 ? 0 : (kk > NPL + 1 ? NPL + 1 : kk);
                while (kk > 0    && alpha_of((float)(kk-1), spv, sr, sd) >  blo) --kk;
                while (kk <= NPL && alpha_of((float)kk,     spv, sr, sd) <= blo) ++kk;
                if (kk - 1 >= 0) {
                    float ap = alpha_of((float)(kk-1), spv, sr, sd);
                    if (ap >= amin && ap > prev) prev = ap;
                }
                nexta[a] = (kk <= NPL) ? alpha_of((float)kk, spv, sr, sd) : INFINITY;
            } else {     // alpha increases as k decreases; pointer = largest k with alpha(k) > blo
                kk = (int)ceilf(kf) - 1;
                kk = kk > NPL ? NPL : (kk < -1 ? -1 : kk);
                while (kk < NPL && alpha_of((float)(kk+1), spv, sr, sd) >  blo) ++kk;
                while (kk >= 0  && alpha_of((float)kk,     spv, sr, sd) <= blo) --kk;
                if (kk + 1 <= NPL) {
                    float ap = alpha_of((float)(kk+1), spv, sr, sd);
                    if (ap >= amin && ap > prev) prev = ap;
                }
                nexta[a] = (kk >= 0) ? alpha_of((float)kk, spv, sr, sd) : INFINITY;
            }
            kcur[a] = kk;
        }

        // 3-way merge over this segment's window
        for (int guard = 0; guard < 1024; ++guard) {
            int ax = 0;
            float q = nexta[0];
            if (nexta[1] < q) { q = nexta[1]; ax = 1; }
            if (nexta[2] < q) { q = nexta[2]; ax = 2; }
            if (!(q <= bhi)) break;

            const float step = q - prev;
            const float amid = 0.5f * (prev + q);

            float p0 = src[0] + amid * sdd[0];
            float p1 = src[1] + amid * sdd[1];
            float p2 = src[2] + amid * sdd[2];
            int i0 = (int)(p0 / spn[0]);
            int i1 = (int)(p1 / spn[1]);
            int i2 = (int)(p2 / spn[2]);
            i0 = i0 < 0 ? 0 : (i0 > 255 ? 255 : i0);
            i1 = i1 < 0 ? 0 : (i1 > 255 ? 255 : i1);
            i2 = i2 < 0 ? 0 : (i2 > 255 ? 255 : i2);

            // vol = volume[::-1] along axis 0
            const float vox = vol[(size_t)(255 - i0) * 65536 + (size_t)i1 * 256 + (size_t)i2];
            acc += step * vox;
            prev = q;

            const int nk = kcur[ax] + kstp[ax];
            kcur[ax] = nk;
            nexta[ax] = (nk >= 0 && nk <= NPL)
                      ? alpha_of((float)nk, spn[ax], src[ax], sdd[ax])
                      : INFINITY;
        }
    }

    // reduce the SPLIT partial sums (consecutive lanes = same ray)
    for (int off = SPLIT / 2; off > 0; off >>= 1)
        acc += __shfl_down(acc, off, SPLIT);

    if (seg == 0) out[ray] = acc * sqrtf(nrm2);
}

extern "C" void kernel_launch(void* const* d_in, const int* in_sizes, int n_in,
                              void* d_out, int out_size, void* d_ws, size_t ws_size,
                              hipStream_t stream)
{
    const float* vol     = (const float*)d_in[0];
    const float* spacing = (const float*)d_in[1];
    const float* sdr     = (const float*)d_in[2];
    const float* theta   = (const float*)d_in[3];
    const float* phi     = (const float*)d_in[4];
    const float* gamma   = (const float*)d_in[5];
    const float* bx      = (const float*)d_in[6];
    const float* by      = (const float*)d_in[7];
    const float* bz      = (const float*)d_in[8];
    float* out = (float*)d_out;

    const int threads = HH * WW * SPLIT;
    const int block   = 256;
    const int grid    = (threads + block - 1) / block;
    drr_kernel<<<grid, block, 0, stream>>>(vol, spacing, sdr, theta, phi, gamma,
                                           bx, by, bz, out);
}

// Round 3
// 61.887 us; speedup vs baseline: 1.7267x; 1.7267x over previous
//
#include <hip/hip_runtime.h>
#include <math.h>

// Match the numpy/JAX reference op-for-op: no FMA contraction anywhere in
// the expressions that feed discrete decisions (alpha values, voxel trunc).
#pragma clang fp contract(off)

#define SPLIT 16
static constexpr int HH = 200, WW = 200, NPL = 256; // planes k = 0..256

__device__ __forceinline__ float alpha_of(float k, float sp, float src, float sdd) {
    return (k * sp - src) / sdd;   // reference: (k*spacing - src)/sdd, mul-sub-div
}

__global__ __launch_bounds__(256)
void drr_kernel(const float* __restrict__ vol,
                const float* __restrict__ spacing,
                const float* __restrict__ sdrP,
                const float* __restrict__ thetaP,
                const float* __restrict__ phiP,
                const float* __restrict__ gammaP,
                const float* __restrict__ bxP,
                const float* __restrict__ byP,
                const float* __restrict__ bzP,
                float* __restrict__ out)
{
    const int tid = blockIdx.x * blockDim.x + threadIdx.x;
    if (tid >= HH * WW * SPLIT) return;
    const int seg = tid / (HH * WW);          // segment in high bits
    const int rid = tid - seg * (HH * WW);    // lanes = consecutive rid
    const int it  = rid % HH;                 // it fastest across lanes -> coalesced i2
    const int is  = rid / HH;

    const float sdr = sdrP[0];
    const float th = thetaP[0], ph = phiP[0], ga = gammaP[0];
    const float ct = cosf(th), st = sinf(th);
    const float cp = cosf(ph), sp = sinf(ph);
    const float cg = cosf(ga), sg = sinf(ga);

    // rotation = Rz @ Ry @ Rx
    const float rot[3][3] = {
        { ct*cp, ct*sp*sg - st*cg, ct*sp*cg + st*sg },
        { st*cp, st*sp*sg + ct*cg, st*sp*cg - ct*sg },
        { -sp,   cp*sg,            cp*cg            }
    };

    float source[3], u[3], v[3], trans[3];
    trans[0] = bxP[0]; trans[1] = byP[0]; trans[2] = bzP[0];
    for (int a = 0; a < 3; ++a) {
        source[a] = sdr * rot[a][0];
        u[a] = (sdr * rot[a][1]) / sdr;
        v[a] = (sdr * rot[a][2]) / sdr;
    }

    const float tc = (float)(it - HH/2 + 1) * 2.0f;   // DELX
    const float sc = (float)(is - WW/2 + 1) * 2.0f;   // DELY

    float src[3], sdd[3], spn[3];
    float nrm2 = 0.0f;
    for (int a = 0; a < 3; ++a) {
        spn[a] = spacing[a];
        src[a] = source[a] + trans[a];
        float tg = tc * u[a] + sc * v[a];
        tg = tg - source[a];     // + center
        tg = tg + trans[a];
        float d = (tg - src[a]) + 1e-8f;   // sdd = tgt - src + EPS
        sdd[a] = d;
        nrm2 = nrm2 + d * d;
    }
    const bool unit = (spn[0] == 1.0f) & (spn[1] == 1.0f) & (spn[2] == 1.0f);

    float amin = -INFINITY, amax = INFINITY;
    for (int a = 0; a < 3; ++a) {
        float a0 = (0.0f - src[a]) / sdd[a];
        float a1 = (256.0f * spn[a] - src[a]) / sdd[a];
        amin = fmaxf(amin, fminf(a0, a1));
        amax = fminf(amax, fmaxf(a0, a1));
    }

    float acc = 0.0f;
    if (amax > amin) {
        // Segment window (blo, bhi]; identical boundary arithmetic in all segs
        // of a ray, so the windows partition (amin, amax] exactly.
        const float blo = (seg == 0) ? amin
                        : amin + (amax - amin) * ((float)seg / (float)SPLIT);
        const float bhi = (seg == SPLIT - 1) ? amax
                        : amin + (amax - amin) * ((float)(seg + 1) / (float)SPLIT);

        float kf[3], kst[3], nexta[3];
        float prev = -INFINITY;   // largest in-range alpha <= blo

        for (int a = 0; a < 3; ++a) {
            const float sd = sdd[a], sr = src[a], spv = spn[a];
            const bool pos = sd > 0.0f;
            kst[a] = pos ? 1.0f : -1.0f;
            const float kseed = (blo * sd + sr) / spv;   // analytic seed
            int kk;
            if (pos) {   // alpha increases with k; pointer = smallest k with alpha(k) > blo
                kk = (int)floorf(kseed) + 1;
                kk = kk < 0 ? 0 : (kk > NPL + 1 ? NPL + 1 : kk);
                while (kk > 0    && alpha_of((float)(kk-1), spv, sr, sd) >  blo) --kk;
                while (kk <= NPL && alpha_of((float)kk,     spv, sr, sd) <= blo) ++kk;
                if (kk - 1 >= 0) {
                    float ap = alpha_of((float)(kk-1), spv, sr, sd);
                    if (ap >= amin && ap > prev) prev = ap;
                }
                nexta[a] = (kk <= NPL) ? alpha_of((float)kk, spv, sr, sd) : INFINITY;
            } else {     // alpha increases as k decreases; pointer = largest k with alpha(k) > blo
                kk = (int)ceilf(kseed) - 1;
                kk = kk > NPL ? NPL : (kk < -1 ? -1 : kk);
                while (kk < NPL && alpha_of((float)(kk+1), spv, sr, sd) >  blo) ++kk;
                while (kk >= 0  && alpha_of((float)kk,     spv, sr, sd) <= blo) --kk;
                if (kk + 1 <= NPL) {
                    float ap = alpha_of((float)(kk+1), spv, sr, sd);
                    if (ap >= amin && ap > prev) prev = ap;
                }
                nexta[a] = (kk >= 0) ? alpha_of((float)kk, spv, sr, sd) : INFINITY;
            }
            kf[a] = (float)kk;
        }

        // 3-way merge over this segment's window (exact ties advance together:
        // zero-width intervals contribute exactly 0 in the reference)
        for (int guard = 0; guard < 1024; ++guard) {
            const float q = fminf(fminf(nexta[0], nexta[1]), nexta[2]);
            if (!(q <= bhi)) break;

            const float step = q - prev;
            const float amid = 0.5f * (prev + q);

            // pts = src + amid * sdd  (reference order: mul, then add — no FMA)
            const float p0 = src[0] + amid * sdd[0];
            const float p1 = src[1] + amid * sdd[1];
            const float p2 = src[2] + amid * sdd[2];
            // idx = trunc(pts / spacing), clip [0,255]. p/1.0 == p exactly.
            float f0, f1, f2;
            if (unit) { f0 = p0; f1 = p1; f2 = p2; }
            else      { f0 = p0 / spn[0]; f1 = p1 / spn[1]; f2 = p2 / spn[2]; }
            f0 = fminf(fmaxf(f0, 0.0f), 255.0f);
            f1 = fminf(fmaxf(f1, 0.0f), 255.0f);
            f2 = fminf(fmaxf(f2, 0.0f), 255.0f);
            const int i0 = (int)f0, i1 = (int)f1, i2 = (int)f2;

            // vol = volume[::-1] along axis 0
            const int addr = ((255 - i0) << 16) | (i1 << 8) | i2;
            acc = fmaf(step, vol[addr], acc);
            prev = q;

            #pragma unroll
            for (int a = 0; a < 3; ++a) {
                if (nexta[a] == q) {
                    const float nk = kf[a] + kst[a];
                    kf[a] = nk;
                    const float al = alpha_of(nk, spn[a], src[a], sdd[a]);
                    nexta[a] = (nk >= 0.0f && nk <= 256.0f) ? al : INFINITY;
                }
            }
        }
    }

    atomicAdd(&out[it * WW + is], acc * sqrtf(nrm2));
}

extern "C" void kernel_launch(void* const* d_in, const int* in_sizes, int n_in,
                              void* d_out, int out_size, void* d_ws, size_t ws_size,
                              hipStream_t stream)
{
    const float* vol     = (const float*)d_in[0];
    const float* spacing = (const float*)d_in[1];
    const float* sdr     = (const float*)d_in[2];
    const float* theta   = (const float*)d_in[3];
    const float* phi     = (const float*)d_in[4];
    const float* gamma   = (const float*)d_in[5];
    const float* bx      = (const float*)d_in[6];
    const float* by      = (const float*)d_in[7];
    const float* bz      = (const float*)d_in[8];
    float* out = (float*)d_out;

    // re-zero the output every replay (graph captures this memset node);
    // required because partial sums are atomically accumulated.
    hipMemsetAsync(out, 0, (size_t)out_size * sizeof(float), stream);

    const int threads = HH * WW * SPLIT;   // 640000 = 2500 * 256 exactly
    const int block   = 256;
    const int grid    = threads / block;
    drr_kernel<<<grid, block, 0, stream>>>(vol, spacing, sdr, theta, phi, gamma,
                                           bx, by, bz, out);
}